// Round 1
// baseline (409.368 us; speedup 1.0000x reference)
//
#include <hip/hip_runtime.h>
#include <stdint.h>

// ---------------- problem constants ----------------
#define BHN 16          // b*h flat batch
#define TLEN 4096
#define EDIM 64
#define NHASH 8
#define NBUCK 64        // buckets per hash
#define GBUCK 512       // global buckets per bh
#define NCHUNK 512
#define NITEMS 32768    // NHASH*TLEN

// ---------------- workspace layout (bytes) ----------------
#define WS_BUCKETS 0u                 // 16*8*4096 u8          = 524288
#define WS_STARTS  524288u            // 16*512 int            = 32768
#define WS_SORTED  557056u            // 16*32768 int          = 2097152
#define WS_LSE     2654208u           // 16*8*4096 f32         = 2097152
#define WS_O       4751360u           // 16*8*4096*64 f32      = 134217728
// total ~139 MB

// ============================================================
// K1: LSH hash. thread = (bh, t); rotations staged in LDS.
// buckets[(bh*8+h)*4096 + t] = argmax over [rot, -rot] (first-max).
// Also histogram via atomics into counts[bh*512 + h*64 + bucket].
// ============================================================
__global__ __launch_bounds__(256) void k_hash(const float* __restrict__ qk,
                                              const float* __restrict__ rot,
                                              uint8_t* __restrict__ buckets,
                                              int* __restrict__ counts) {
  __shared__ __attribute__((aligned(16))) float rot_s[64 * 256]; // [f][h*32+i]
  int tid = threadIdx.x;
  for (int k = tid; k < 16384 / 4; k += 256)
    ((float4*)rot_s)[k] = ((const float4*)rot)[k];
  __syncthreads();

  int gid = blockIdx.x * 256 + tid;          // < 65536
  int bh = gid >> 12;
  int t  = gid & 4095;
  int b = bh >> 3, head = bh & 7;

  const float4* row4 = (const float4*)(qk + ((size_t)((b * 4096 + t) * 8 + head)) * 64);
  float q[64];
#pragma unroll
  for (int f4 = 0; f4 < 16; ++f4) {
    float4 vv = row4[f4];
    q[4 * f4 + 0] = vv.x; q[4 * f4 + 1] = vv.y;
    q[4 * f4 + 2] = vv.z; q[4 * f4 + 3] = vv.w;
  }

  for (int h = 0; h < NHASH; ++h) {
    float acc[32];
#pragma unroll
    for (int i = 0; i < 32; ++i) acc[i] = 0.f;
    const float* rb = rot_s + h * 32;
#pragma unroll
    for (int f = 0; f < 64; ++f) {
      float qf = q[f];
      const float4* rp = (const float4*)(rb + f * 256);
#pragma unroll
      for (int i4 = 0; i4 < 8; ++i4) {
        float4 rv = rp[i4];
        acc[4 * i4 + 0] = fmaf(qf, rv.x, acc[4 * i4 + 0]);
        acc[4 * i4 + 1] = fmaf(qf, rv.y, acc[4 * i4 + 1]);
        acc[4 * i4 + 2] = fmaf(qf, rv.z, acc[4 * i4 + 2]);
        acc[4 * i4 + 3] = fmaf(qf, rv.w, acc[4 * i4 + 3]);
      }
    }
    // argmax over concat([rot, -rot]) in index order (first occurrence of max)
    float bv = acc[0]; int bi = 0;
#pragma unroll
    for (int i = 1; i < 32; ++i) { if (acc[i] > bv) { bv = acc[i]; bi = i; } }
#pragma unroll
    for (int i = 0; i < 32; ++i) { float nv = -acc[i]; if (nv > bv) { bv = nv; bi = i + 32; } }

    buckets[(bh * 8 + h) * 4096 + t] = (uint8_t)bi;
    atomicAdd(&counts[bh * 512 + h * 64 + bi], 1);
  }
}

// ============================================================
// K2a: exclusive scan of 512 bucket counts per bh (in-place).
// ============================================================
__global__ __launch_bounds__(512) void k_scan(int* __restrict__ counts) {
  __shared__ int s[512];
  int tid = threadIdx.x;
  int bh = blockIdx.x;
  s[tid] = counts[bh * 512 + tid];
  __syncthreads();
#pragma unroll
  for (int off = 1; off < 512; off <<= 1) {
    int v = (tid >= off) ? s[tid - off] : 0;
    __syncthreads();
    s[tid] += v;
    __syncthreads();
  }
  counts[bh * 512 + tid] = (tid == 0) ? 0 : s[tid - 1];
}

// ============================================================
// K2b: stable rank within bucket + scatter sorted item ids.
// One block per (bh, hash), 64 threads. Chunked multisplit:
// thread c owns items t in [c*64, c*64+64); local ranks then
// per-bin exclusive prefix across chunks.
// ============================================================
__global__ __launch_bounds__(64) void k_rank(const uint8_t* __restrict__ buckets,
                                             const int* __restrict__ starts,
                                             int* __restrict__ sorted) {
  __shared__ uint8_t bkt[4096];
  __shared__ uint8_t lrk[4096];
  __shared__ int hist[64 * 65];
  __shared__ int sbase[64];
  int tid = threadIdx.x;
  int bh = blockIdx.x >> 3, h = blockIdx.x & 7;

  const int* src = (const int*)(buckets + (size_t)(bh * 8 + h) * 4096);
  for (int k = tid; k < 1024; k += 64) ((int*)bkt)[k] = src[k];
  sbase[tid] = starts[bh * 512 + h * 64 + tid];
  for (int k = tid; k < 64 * 65; k += 64) hist[k] = 0;
  __syncthreads();

  {
    int c = tid;
    for (int k = 0; k < 64; ++k) {
      int t = c * 64 + k;
      int bin = bkt[t];
      int r = hist[c * 65 + bin];
      hist[c * 65 + bin] = r + 1;
      lrk[t] = (uint8_t)r;
    }
  }
  __syncthreads();
  {
    int bb = tid; int run = 0;
    for (int c2 = 0; c2 < 64; ++c2) {
      int val = hist[c2 * 65 + bb];
      hist[c2 * 65 + bb] = run;
      run += val;
    }
  }
  __syncthreads();
  {
    int c = tid;
    int* dst = sorted + (size_t)bh * 32768;
    for (int k = 0; k < 64; ++k) {
      int t = c * 64 + k;
      int bin = bkt[t];
      int pos = sbase[bin] + hist[c * 65 + bin] + (int)lrk[t];
      dst[pos] = h * 4096 + t;   // item id; key order == (bucket, t)
    }
  }
}

// ============================================================
// K3: chunked attention. block = (bh, chunk), 256 threads.
// sh: phase 1 = K^T normalized [f=64][row=128] (stride 132),
//     phase 2 = P row-major [q=64][j=128] (stride 132).
// vv: V rows [128][64].
// dots: thread tile 8q x 4k (8 groups x 32 lanes).
// PV:   thread tile 4q x 4d (16 x 16).
// ============================================================
__global__ __launch_bounds__(256) void k_attn(const float* __restrict__ qk,
                                              const float* __restrict__ vin,
                                              const int* __restrict__ sorted,
                                              float* __restrict__ o_buf,
                                              float* __restrict__ lse_buf) {
  __shared__ __attribute__((aligned(16))) float sh[64 * 132];
  __shared__ __attribute__((aligned(16))) float vv[128 * 64];
  __shared__ float norms[128];
  __shared__ int tv[128];
  __shared__ int items[64];

  int tid = threadIdx.x;
  int bh = blockIdx.x >> 9;
  int c  = blockIdx.x & 511;
  int b = bh >> 3, head = bh & 7;

  // ---- step 1: item ids for 64 current + 64 look-back rows ----
  if (tid < 128) {
    int r = tid;
    int pos = (r < 64) ? (c * 64 + r) : (((c + 511) & 511) * 64 + (r - 64));
    int item = sorted[(size_t)bh * 32768 + pos];
    tv[r] = item & 4095;
    if (r < 64) items[r] = item;
  }
  __syncthreads();

  // ---- step 2: gather rows (qk -> sh transposed, v -> vv) ----
  {
    int r = tid >> 1, half = tid & 1;
    int t = tv[r];
    size_t base = ((size_t)((b * 4096 + t) * 8 + head)) * 64 + half * 32;
    const float4* q4 = (const float4*)(qk + base);
    const float4* v4 = (const float4*)(vin + base);
#pragma unroll
    for (int j = 0; j < 8; ++j) {
      float4 qv = q4[j];
      int f0 = half * 32 + 4 * j;
      sh[(f0 + 0) * 132 + r] = qv.x;
      sh[(f0 + 1) * 132 + r] = qv.y;
      sh[(f0 + 2) * 132 + r] = qv.z;
      sh[(f0 + 3) * 132 + r] = qv.w;
      *(float4*)&vv[r * 64 + f0] = v4[j];
    }
  }
  __syncthreads();

  // ---- step 3: normalize all 128 rows, keep norms ----
  if (tid < 128) {
    int r = tid;
    float s = 0.f;
    for (int f = 0; f < 64; ++f) { float x = sh[f * 132 + r]; s = fmaf(x, x, s); }
    float n = fmaxf(sqrtf(s), 1e-12f);
    norms[r] = n;
    float inv = 1.f / n;
    for (int f = 0; f < 64; ++f) sh[f * 132 + r] *= inv;
  }
  __syncthreads();

  // ---- step 4: dots (raw q = norm * normalized q) ----
  int g = tid >> 5, lane = tid & 31;
  int qi0 = g * 8, kj0 = lane * 4;
  float acc[8][4];
#pragma unroll
  for (int r = 0; r < 8; ++r)
#pragma unroll
    for (int k = 0; k < 4; ++k) acc[r][k] = 0.f;

  for (int f = 0; f < 64; ++f) {
    float4 kv = *(const float4*)&sh[f * 132 + kj0];
    float4 qa = *(const float4*)&sh[f * 132 + qi0];
    float4 qb = *(const float4*)&sh[f * 132 + qi0 + 4];
    float qr[8] = {qa.x, qa.y, qa.z, qa.w, qb.x, qb.y, qb.z, qb.w};
    float kr[4] = {kv.x, kv.y, kv.z, kv.w};
#pragma unroll
    for (int r = 0; r < 8; ++r)
#pragma unroll
      for (int k = 0; k < 4; ++k)
        acc[r][k] = fmaf(qr[r], kr[k], acc[r][k]);
  }

  // scale by query norm, apply self-mask
  float scq[8]; int tq[8]; int tk[4];
#pragma unroll
  for (int r = 0; r < 8; ++r) { scq[r] = norms[qi0 + r]; tq[r] = tv[qi0 + r]; }
#pragma unroll
  for (int k = 0; k < 4; ++k) tk[k] = tv[kj0 + k];
#pragma unroll
  for (int r = 0; r < 8; ++r)
#pragma unroll
    for (int k = 0; k < 4; ++k) {
      float d = acc[r][k] * scq[r];
      if (tk[k] == tq[r]) d = -50000.0f;
      acc[r][k] = d;
    }

  // ---- softmax per query row (across 32-lane group) ----
  float lse_r[8];
#pragma unroll
  for (int r = 0; r < 8; ++r) {
    float m = fmaxf(fmaxf(acc[r][0], acc[r][1]), fmaxf(acc[r][2], acc[r][3]));
    m = fmaxf(m, __shfl_xor(m, 1));
    m = fmaxf(m, __shfl_xor(m, 2));
    m = fmaxf(m, __shfl_xor(m, 4));
    m = fmaxf(m, __shfl_xor(m, 8));
    m = fmaxf(m, __shfl_xor(m, 16));
    float e0 = __expf(acc[r][0] - m);
    float e1 = __expf(acc[r][1] - m);
    float e2 = __expf(acc[r][2] - m);
    float e3 = __expf(acc[r][3] - m);
    float s = e0 + e1 + e2 + e3;
    s += __shfl_xor(s, 1);
    s += __shfl_xor(s, 2);
    s += __shfl_xor(s, 4);
    s += __shfl_xor(s, 8);
    s += __shfl_xor(s, 16);
    float inv = 1.f / s;
    acc[r][0] = e0 * inv; acc[r][1] = e1 * inv;
    acc[r][2] = e2 * inv; acc[r][3] = e3 * inv;
    lse_r[r] = m + __logf(s);
  }
  if (lane == 0) {
#pragma unroll
    for (int r = 0; r < 8; ++r) {
      int item = items[qi0 + r];
      lse_buf[(size_t)(bh * 8 + (item >> 12)) * 4096 + (item & 4095)] = lse_r[r];
    }
  }
  __syncthreads();   // everyone done reading K^T from sh

  // ---- write P row-major [q][j], stride 132 ----
#pragma unroll
  for (int r = 0; r < 8; ++r)
    *(float4*)&sh[(qi0 + r) * 132 + kj0] =
        make_float4(acc[r][0], acc[r][1], acc[r][2], acc[r][3]);
  __syncthreads();

  // ---- PV: thread tile 4q x 4d ----
  int qt = tid >> 4, dt = tid & 15;
  float acc2[4][4];
#pragma unroll
  for (int r = 0; r < 4; ++r)
#pragma unroll
    for (int d = 0; d < 4; ++d) acc2[r][d] = 0.f;

  for (int j4 = 0; j4 < 32; ++j4) {
    float4 p0 = *(const float4*)&sh[(qt * 4 + 0) * 132 + j4 * 4];
    float4 p1 = *(const float4*)&sh[(qt * 4 + 1) * 132 + j4 * 4];
    float4 p2 = *(const float4*)&sh[(qt * 4 + 2) * 132 + j4 * 4];
    float4 p3 = *(const float4*)&sh[(qt * 4 + 3) * 132 + j4 * 4];
    float4 w0 = *(const float4*)&vv[(j4 * 4 + 0) * 64 + dt * 4];
    float4 w1 = *(const float4*)&vv[(j4 * 4 + 1) * 64 + dt * 4];
    float4 w2 = *(const float4*)&vv[(j4 * 4 + 2) * 64 + dt * 4];
    float4 w3 = *(const float4*)&vv[(j4 * 4 + 3) * 64 + dt * 4];
    float pm[4][4] = {{p0.x, p0.y, p0.z, p0.w}, {p1.x, p1.y, p1.z, p1.w},
                      {p2.x, p2.y, p2.z, p2.w}, {p3.x, p3.y, p3.z, p3.w}};
    float vm[4][4] = {{w0.x, w0.y, w0.z, w0.w}, {w1.x, w1.y, w1.z, w1.w},
                      {w2.x, w2.y, w2.z, w2.w}, {w3.x, w3.y, w3.z, w3.w}};
#pragma unroll
    for (int r = 0; r < 4; ++r)
#pragma unroll
      for (int jj = 0; jj < 4; ++jj)
#pragma unroll
        for (int d = 0; d < 4; ++d)
          acc2[r][d] = fmaf(pm[r][jj], vm[jj][d], acc2[r][d]);
  }

  // ---- scatter o to [bh][hash][t][d] ----
#pragma unroll
  for (int r = 0; r < 4; ++r) {
    int row = qt * 4 + r;
    int item = items[row];
    int hash = item >> 12;
    int tt = item & 4095;
    *(float4*)(o_buf + ((size_t)((bh * 8 + hash) * 4096 + tt)) * 64 + dt * 4) =
        make_float4(acc2[r][0], acc2[r][1], acc2[r][2], acc2[r][3]);
  }
}

// ============================================================
// K4: combine 8 hash rounds: softmax over per-round lse.
// thread handles 4 output dims.
// ============================================================
__global__ __launch_bounds__(256) void k_combine(const float* __restrict__ o_buf,
                                                 const float* __restrict__ lse_buf,
                                                 float* __restrict__ out) {
  int gid = blockIdx.x * 256 + threadIdx.x;  // < 16*4096*16
  int d4 = gid & 15;
  int t  = (gid >> 4) & 4095;
  int bh = gid >> 16;

  float l[8];
#pragma unroll
  for (int h = 0; h < 8; ++h) l[h] = lse_buf[(size_t)(bh * 8 + h) * 4096 + t];
  float m = l[0];
#pragma unroll
  for (int h = 1; h < 8; ++h) m = fmaxf(m, l[h]);
  float w[8]; float s = 0.f;
#pragma unroll
  for (int h = 0; h < 8; ++h) { w[h] = __expf(l[h] - m); s += w[h]; }
  float inv = 1.f / s;

  float ax = 0.f, ay = 0.f, az = 0.f, aw = 0.f;
#pragma unroll
  for (int h = 0; h < 8; ++h) {
    float4 ov = *(const float4*)(o_buf +
        ((size_t)((bh * 8 + h) * 4096 + t)) * 64 + d4 * 4);
    ax = fmaf(w[h], ov.x, ax);
    ay = fmaf(w[h], ov.y, ay);
    az = fmaf(w[h], ov.z, az);
    aw = fmaf(w[h], ov.w, aw);
  }
  *(float4*)(out + ((size_t)(bh * 4096 + t)) * 64 + d4 * 4) =
      make_float4(ax * inv, ay * inv, az * inv, aw * inv);
}

// ============================================================
extern "C" void kernel_launch(void* const* d_in, const int* in_sizes, int n_in,
                              void* d_out, int out_size, void* d_ws, size_t ws_size,
                              hipStream_t stream) {
  const float* qk  = (const float*)d_in[0];
  // d_in[1] ("k") is unused by the reference
  const float* vin = (const float*)d_in[2];
  const float* rot = (const float*)d_in[3];

  uint8_t* ws = (uint8_t*)d_ws;
  uint8_t* buckets = ws + WS_BUCKETS;
  int*     counts  = (int*)(ws + WS_STARTS);
  int*     sorted  = (int*)(ws + WS_SORTED);
  float*   lse_buf = (float*)(ws + WS_LSE);
  float*   o_buf   = (float*)(ws + WS_O);
  float*   out     = (float*)d_out;

  hipMemsetAsync(counts, 0, BHN * GBUCK * sizeof(int), stream);
  k_hash<<<256, 256, 0, stream>>>(qk, rot, buckets, counts);
  k_scan<<<BHN, 512, 0, stream>>>(counts);
  k_rank<<<BHN * NHASH, 64, 0, stream>>>(buckets, counts, sorted);
  k_attn<<<BHN * NCHUNK, 256, 0, stream>>>(qk, vin, sorted, o_buf, lse_buf);
  k_combine<<<4096, 256, 0, stream>>>(o_buf, lse_buf, out);
}

// Round 2
// 211.152 us; speedup vs baseline: 1.9387x; 1.9387x over previous
//
#include <hip/hip_runtime.h>
#include <stdint.h>

// ---------------- problem constants ----------------
#define BHN 16          // b*h flat batch
#define TLEN 4096
#define EDIM 64
#define NHASH 8
#define NBUCK 64        // buckets per hash
#define GBUCK 512       // global buckets per bh
#define NCHUNK 512
#define NITEMS 32768    // NHASH*TLEN

// ---------------- workspace layout (bytes) ----------------
#define WS_BUCKETS 0u                 // 16*8*4096 u8          = 524288
#define WS_STARTS  524288u            // 16*512 int            = 32768
#define WS_SORTED  557056u            // 16*32768 int          = 2097152
#define WS_LSE     2654208u           // 16*8*4096 f32         = 2097152
#define WS_O       4751360u           // 16*8*4096*64 f32      = 134217728

typedef __attribute__((ext_vector_type(4))) float f32x4;
typedef __attribute__((ext_vector_type(8))) short bf16x8;       // MFMA A/B frag
typedef __attribute__((ext_vector_type(8))) unsigned short u16x8;
typedef __attribute__((ext_vector_type(4))) unsigned short u16x4;

static __device__ __forceinline__ unsigned short f2bf_rne(float f) {
  unsigned u = __float_as_uint(f);
  return (unsigned short)((u + 0x7fffu + ((u >> 16) & 1u)) >> 16);
}

// ============================================================
// K1: LSH hash (unchanged from round 0)
// ============================================================
__global__ __launch_bounds__(256) void k_hash(const float* __restrict__ qk,
                                              const float* __restrict__ rot,
                                              uint8_t* __restrict__ buckets,
                                              int* __restrict__ counts) {
  __shared__ __attribute__((aligned(16))) float rot_s[64 * 256]; // [f][h*32+i]
  int tid = threadIdx.x;
  for (int k = tid; k < 16384 / 4; k += 256)
    ((float4*)rot_s)[k] = ((const float4*)rot)[k];
  __syncthreads();

  int gid = blockIdx.x * 256 + tid;          // < 65536
  int bh = gid >> 12;
  int t  = gid & 4095;
  int b = bh >> 3, head = bh & 7;

  const float4* row4 = (const float4*)(qk + ((size_t)((b * 4096 + t) * 8 + head)) * 64);
  float q[64];
#pragma unroll
  for (int f4 = 0; f4 < 16; ++f4) {
    float4 vv = row4[f4];
    q[4 * f4 + 0] = vv.x; q[4 * f4 + 1] = vv.y;
    q[4 * f4 + 2] = vv.z; q[4 * f4 + 3] = vv.w;
  }

  for (int h = 0; h < NHASH; ++h) {
    float acc[32];
#pragma unroll
    for (int i = 0; i < 32; ++i) acc[i] = 0.f;
    const float* rb = rot_s + h * 32;
#pragma unroll
    for (int f = 0; f < 64; ++f) {
      float qf = q[f];
      const float4* rp = (const float4*)(rb + f * 256);
#pragma unroll
      for (int i4 = 0; i4 < 8; ++i4) {
        float4 rv = rp[i4];
        acc[4 * i4 + 0] = fmaf(qf, rv.x, acc[4 * i4 + 0]);
        acc[4 * i4 + 1] = fmaf(qf, rv.y, acc[4 * i4 + 1]);
        acc[4 * i4 + 2] = fmaf(qf, rv.z, acc[4 * i4 + 2]);
        acc[4 * i4 + 3] = fmaf(qf, rv.w, acc[4 * i4 + 3]);
      }
    }
    float bv = acc[0]; int bi = 0;
#pragma unroll
    for (int i = 1; i < 32; ++i) { if (acc[i] > bv) { bv = acc[i]; bi = i; } }
#pragma unroll
    for (int i = 0; i < 32; ++i) { float nv = -acc[i]; if (nv > bv) { bv = nv; bi = i + 32; } }

    buckets[(bh * 8 + h) * 4096 + t] = (uint8_t)bi;
    atomicAdd(&counts[bh * 512 + h * 64 + bi], 1);
  }
}

// ============================================================
// K2a: exclusive scan (unchanged)
// ============================================================
__global__ __launch_bounds__(512) void k_scan(int* __restrict__ counts) {
  __shared__ int s[512];
  int tid = threadIdx.x;
  int bh = blockIdx.x;
  s[tid] = counts[bh * 512 + tid];
  __syncthreads();
#pragma unroll
  for (int off = 1; off < 512; off <<= 1) {
    int v = (tid >= off) ? s[tid - off] : 0;
    __syncthreads();
    s[tid] += v;
    __syncthreads();
  }
  counts[bh * 512 + tid] = (tid == 0) ? 0 : s[tid - 1];
}

// ============================================================
// K2b: stable rank + scatter (unchanged)
// ============================================================
__global__ __launch_bounds__(64) void k_rank(const uint8_t* __restrict__ buckets,
                                             const int* __restrict__ starts,
                                             int* __restrict__ sorted) {
  __shared__ uint8_t bkt[4096];
  __shared__ uint8_t lrk[4096];
  __shared__ int hist[64 * 65];
  __shared__ int sbase[64];
  int tid = threadIdx.x;
  int bh = blockIdx.x >> 3, h = blockIdx.x & 7;

  const int* src = (const int*)(buckets + (size_t)(bh * 8 + h) * 4096);
  for (int k = tid; k < 1024; k += 64) ((int*)bkt)[k] = src[k];
  sbase[tid] = starts[bh * 512 + h * 64 + tid];
  for (int k = tid; k < 64 * 65; k += 64) hist[k] = 0;
  __syncthreads();

  {
    int c = tid;
    for (int k = 0; k < 64; ++k) {
      int t = c * 64 + k;
      int bin = bkt[t];
      int r = hist[c * 65 + bin];
      hist[c * 65 + bin] = r + 1;
      lrk[t] = (uint8_t)r;
    }
  }
  __syncthreads();
  {
    int bb = tid; int run = 0;
    for (int c2 = 0; c2 < 64; ++c2) {
      int val = hist[c2 * 65 + bb];
      hist[c2 * 65 + bb] = run;
      run += val;
    }
  }
  __syncthreads();
  {
    int c = tid;
    int* dst = sorted + (size_t)bh * 32768;
    for (int k = 0; k < 64; ++k) {
      int t = c * 64 + k;
      int bin = bkt[t];
      int pos = sbase[bin] + hist[c * 65 + bin] + (int)lrk[t];
      dst[pos] = h * 4096 + t;
    }
  }
}

// ============================================================
// K3: chunked attention via split-bf16 MFMA.
// block = (bh, chunk), 256 threads = 4 waves.
// khi/klo: K-tile rows [j=128][f=64] bf16 (hi/lo), 16B slots
//          XOR-swizzled: slot' = slot ^ (row&7).
// vt:      V^T [d=64][j=128] bf16, slot' = slot ^ (d&15).
// P buffer [q=64][j=128] bf16 ALIASES khi (after barrier),
//          slot' = slot ^ (q&15).
// Wave w owns q-columns w*16..w*16+15.
// Dots: S^T[j][q] = sum_f K[j][f] Q[q][f] (A=K rows, B=Q^T),
//       3 MFMAs per k-step (hi*hi + hi*lo + lo*hi).
// PV:   O[q][d] = sum_j P[q][j] V[j][d] (A=P, B=V^T), bf16.
// ============================================================
__global__ __launch_bounds__(256, 3) void k_attn(const float* __restrict__ qk,
                                                 const float* __restrict__ vin,
                                                 const int* __restrict__ sorted,
                                                 float* __restrict__ o_buf,
                                                 float* __restrict__ lse_buf) {
  __shared__ __attribute__((aligned(16))) unsigned short khi[128 * 64];
  __shared__ __attribute__((aligned(16))) unsigned short klo[128 * 64];
  __shared__ __attribute__((aligned(16))) unsigned short vt[64 * 128];
  __shared__ __attribute__((aligned(16))) float norms_inv[128];
  __shared__ __attribute__((aligned(16))) int tv[128];
  __shared__ __attribute__((aligned(16))) int items[64];

  int tid = threadIdx.x;
  int bh = blockIdx.x >> 9;
  int c  = blockIdx.x & 511;
  int b = bh >> 3, head = bh & 7;

  // ---- step 1: item ids for 64 current + 64 look-back rows ----
  if (tid < 128) {
    int r = tid;
    int pos = (r < 64) ? (c * 64 + r) : (((c + 511) & 511) * 64 + (r - 64));
    int item = sorted[(size_t)bh * 32768 + pos];
    tv[r] = item & 4095;
    if (r < 64) items[r] = item;
  }
  __syncthreads();

  // ---- step 2a: gather K/Q rows -> khi/klo (split bf16), norms ----
  {
    int r = tid >> 1, h = tid & 1;
    int t = tv[r];
    const float4* src = (const float4*)(qk + ((size_t)((b * 4096 + t) * 8 + head)) * 64 + h * 32);
    float x[32];
    float ss = 0.f;
#pragma unroll
    for (int i = 0; i < 8; ++i) {
      float4 v = src[i];
      x[4 * i + 0] = v.x; x[4 * i + 1] = v.y; x[4 * i + 2] = v.z; x[4 * i + 3] = v.w;
      ss = fmaf(v.x, v.x, ss); ss = fmaf(v.y, v.y, ss);
      ss = fmaf(v.z, v.z, ss); ss = fmaf(v.w, v.w, ss);
    }
    ss += __shfl_xor(ss, 1);
    if (h == 0) norms_inv[r] = 1.f / fmaxf(sqrtf(ss), 1e-12f);
    int rx = r & 7;
#pragma unroll
    for (int s4 = 0; s4 < 4; ++s4) {
      int slot = 4 * h + s4;
      u16x8 hv, lv;
#pragma unroll
      for (int e = 0; e < 8; ++e) {
        float xv = x[8 * s4 + e];
        unsigned u = __float_as_uint(xv);
        hv[e] = (unsigned short)(u >> 16);
        float hf = __uint_as_float(u & 0xffff0000u);
        float lo = xv - hf;
        lv[e] = (unsigned short)(__float_as_uint(lo) >> 16);
      }
      int off = r * 64 + ((slot ^ rx) << 3);
      *(u16x8*)&khi[off] = hv;
      *(u16x8*)&klo[off] = lv;
    }
  }

  // ---- step 2b: gather V -> vt (transposed, bf16 RNE) ----
  {
    int jp = tid & 63, cq = tid >> 6, f0 = cq * 16;
    int t0 = tv[2 * jp], t1 = tv[2 * jp + 1];
    const float4* s0 = (const float4*)(vin + ((size_t)((b * 4096 + t0) * 8 + head)) * 64 + f0);
    const float4* s1 = (const float4*)(vin + ((size_t)((b * 4096 + t1) * 8 + head)) * 64 + f0);
    float y0[16], y1[16];
#pragma unroll
    for (int i = 0; i < 4; ++i) {
      float4 a = s0[i], bb2 = s1[i];
      y0[4 * i + 0] = a.x; y0[4 * i + 1] = a.y; y0[4 * i + 2] = a.z; y0[4 * i + 3] = a.w;
      y1[4 * i + 0] = bb2.x; y1[4 * i + 1] = bb2.y; y1[4 * i + 2] = bb2.z; y1[4 * i + 3] = bb2.w;
    }
#pragma unroll
    for (int i = 0; i < 16; ++i) {
      int d = f0 + i;
      unsigned pack = (unsigned)f2bf_rne(y0[i]) | ((unsigned)f2bf_rne(y1[i]) << 16);
      *(unsigned*)&vt[d * 128 + (((jp >> 2) ^ (d & 15)) << 3) + ((jp & 3) << 1)] = pack;
    }
  }
  __syncthreads();

  // ---- step 3: dots S^T = K * Q^T (split-bf16, 3 MFMAs per step) ----
  int w = tid >> 6;
  int l = tid & 63;
  int col = l & 15;
  int kg = l >> 4;
  int rq = w * 16 + col;       // this lane's q row (B-frag col / P row)
  int rqx7 = rq & 7, rqx15 = rq & 15;

  bf16x8 qh[2], ql[2];
#pragma unroll
  for (int ks = 0; ks < 2; ++ks) {
    int off = rq * 64 + (((ks * 4 + kg) ^ rqx7) << 3);
    qh[ks] = *(bf16x8*)&khi[off];
    ql[ks] = *(bf16x8*)&klo[off];
  }

  f32x4 S[8];
#pragma unroll
  for (int mt = 0; mt < 8; ++mt) S[mt] = (f32x4){0.f, 0.f, 0.f, 0.f};

#pragma unroll
  for (int mt = 0; mt < 8; ++mt) {
    int rj = mt * 16 + col;
    int rjx = rj & 7;
#pragma unroll
    for (int ks = 0; ks < 2; ++ks) {
      int off = rj * 64 + (((ks * 4 + kg) ^ rjx) << 3);
      bf16x8 ah = *(bf16x8*)&khi[off];
      bf16x8 al = *(bf16x8*)&klo[off];
      S[mt] = __builtin_amdgcn_mfma_f32_16x16x32_bf16(ah, qh[ks], S[mt], 0, 0, 0);
      S[mt] = __builtin_amdgcn_mfma_f32_16x16x32_bf16(ah, ql[ks], S[mt], 0, 0, 0);
      S[mt] = __builtin_amdgcn_mfma_f32_16x16x32_bf16(al, qh[ks], S[mt], 0, 0, 0);
    }
  }

  // ---- step 4: scale by inv_norm[j], self-mask, softmax over j ----
  int tq = tv[rq];
  float vals[32];
  float mx = -1e30f;
#pragma unroll
  for (int mt = 0; mt < 8; ++mt) {
    int j0 = mt * 16 + kg * 4;
    int4   tk4 = *(int4*)&tv[j0];
    float4 ni4 = *(float4*)&norms_inv[j0];
    int   tki[4] = {tk4.x, tk4.y, tk4.z, tk4.w};
    float nii[4] = {ni4.x, ni4.y, ni4.z, ni4.w};
#pragma unroll
    for (int r = 0; r < 4; ++r) {
      float d = S[mt][r] * nii[r];
      if (tki[r] == tq) d = -50000.0f;
      vals[mt * 4 + r] = d;
      mx = fmaxf(mx, d);
    }
  }
  mx = fmaxf(mx, __shfl_xor(mx, 16));
  mx = fmaxf(mx, __shfl_xor(mx, 32));
  float ssum = 0.f;
#pragma unroll
  for (int i = 0; i < 32; ++i) {
    float e = __expf(vals[i] - mx);
    vals[i] = e;
    ssum += e;
  }
  ssum += __shfl_xor(ssum, 16);
  ssum += __shfl_xor(ssum, 32);
  float pinv = 1.f / ssum;
  if (kg == 0) {
    int item = items[rq];
    lse_buf[(size_t)(bh * 8 + (item >> 12)) * 4096 + (item & 4095)] = mx + __logf(ssum);
  }

  __syncthreads();   // all waves done reading khi/klo as K/Q

  // ---- step 5: write P (bf16) into khi alias ----
  unsigned short* Pb = khi;
#pragma unroll
  for (int mt = 0; mt < 8; ++mt) {
    int j0 = mt * 16 + kg * 4;
    int slot = j0 >> 3;                    // 2*mt + (kg>>1)
    int off = rq * 128 + ((slot ^ rqx15) << 3) + ((kg & 1) << 2);
    u16x4 pk;
#pragma unroll
    for (int r = 0; r < 4; ++r) pk[r] = f2bf_rne(vals[mt * 4 + r] * pinv);
    *(u16x4*)&Pb[off] = pk;
  }
  asm volatile("s_waitcnt lgkmcnt(0)" ::: "memory");  // own-wave writes visible

  // ---- step 6: PV = P * V (A = P rows, B = V^T rows) ----
  f32x4 O[4];
#pragma unroll
  for (int nt = 0; nt < 4; ++nt) O[nt] = (f32x4){0.f, 0.f, 0.f, 0.f};
#pragma unroll
  for (int ks = 0; ks < 4; ++ks) {
    int slot = (ks << 2) + kg;
    bf16x8 pa = *(bf16x8*)&Pb[rq * 128 + ((slot ^ rqx15) << 3)];
#pragma unroll
    for (int nt = 0; nt < 4; ++nt) {
      int dD = nt * 16 + col;
      bf16x8 vb = *(bf16x8*)&vt[dD * 128 + ((slot ^ (dD & 15)) << 3)];
      O[nt] = __builtin_amdgcn_mfma_f32_16x16x32_bf16(pa, vb, O[nt], 0, 0, 0);
    }
  }

  // ---- step 7: scatter O rows to o_buf[bh][hash][t][d] ----
  {
    int i0 = w * 16 + kg * 4;
    int4 it4 = *(int4*)&items[i0];
    int iti[4] = {it4.x, it4.y, it4.z, it4.w};
#pragma unroll
    for (int r = 0; r < 4; ++r) {
      int item = iti[r];
      float* orow = o_buf + ((size_t)((bh * 8 + (item >> 12)) * 4096 + (item & 4095))) * 64;
#pragma unroll
      for (int nt = 0; nt < 4; ++nt) orow[nt * 16 + col] = O[nt][r];
    }
  }
}

// ============================================================
// K4: combine 8 hash rounds (unchanged)
// ============================================================
__global__ __launch_bounds__(256) void k_combine(const float* __restrict__ o_buf,
                                                 const float* __restrict__ lse_buf,
                                                 float* __restrict__ out) {
  int gid = blockIdx.x * 256 + threadIdx.x;  // < 16*4096*16
  int d4 = gid & 15;
  int t  = (gid >> 4) & 4095;
  int bh = gid >> 16;

  float lx[8];
#pragma unroll
  for (int h = 0; h < 8; ++h) lx[h] = lse_buf[(size_t)(bh * 8 + h) * 4096 + t];
  float m = lx[0];
#pragma unroll
  for (int h = 1; h < 8; ++h) m = fmaxf(m, lx[h]);
  float wv[8]; float s = 0.f;
#pragma unroll
  for (int h = 0; h < 8; ++h) { wv[h] = __expf(lx[h] - m); s += wv[h]; }
  float inv = 1.f / s;

  float ax = 0.f, ay = 0.f, az = 0.f, aw = 0.f;
#pragma unroll
  for (int h = 0; h < 8; ++h) {
    float4 ov = *(const float4*)(o_buf +
        ((size_t)((bh * 8 + h) * 4096 + t)) * 64 + d4 * 4);
    ax = fmaf(wv[h], ov.x, ax);
    ay = fmaf(wv[h], ov.y, ay);
    az = fmaf(wv[h], ov.z, az);
    aw = fmaf(wv[h], ov.w, aw);
  }
  *(float4*)(out + ((size_t)(bh * 4096 + t)) * 64 + d4 * 4) =
      make_float4(ax * inv, ay * inv, az * inv, aw * inv);
}

// ============================================================
extern "C" void kernel_launch(void* const* d_in, const int* in_sizes, int n_in,
                              void* d_out, int out_size, void* d_ws, size_t ws_size,
                              hipStream_t stream) {
  const float* qk  = (const float*)d_in[0];
  // d_in[1] ("k") is unused by the reference
  const float* vin = (const float*)d_in[2];
  const float* rot = (const float*)d_in[3];

  uint8_t* ws = (uint8_t*)d_ws;
  uint8_t* buckets = ws + WS_BUCKETS;
  int*     counts  = (int*)(ws + WS_STARTS);
  int*     sorted  = (int*)(ws + WS_SORTED);
  float*   lse_buf = (float*)(ws + WS_LSE);
  float*   o_buf   = (float*)(ws + WS_O);
  float*   out     = (float*)d_out;

  hipMemsetAsync(counts, 0, BHN * GBUCK * sizeof(int), stream);
  k_hash<<<256, 256, 0, stream>>>(qk, rot, buckets, counts);
  k_scan<<<BHN, 512, 0, stream>>>(counts);
  k_rank<<<BHN * NHASH, 64, 0, stream>>>(buckets, counts, sorted);
  k_attn<<<BHN * NCHUNK, 256, 0, stream>>>(qk, vin, sorted, o_buf, lse_buf);
  k_combine<<<4096, 256, 0, stream>>>(o_buf, lse_buf, out);
}